// Round 5
// baseline (83.433 us; speedup 1.0000x reference)
//
#include <hip/hip_runtime.h>

typedef __attribute__((ext_vector_type(4))) float f32x4;
typedef __attribute__((ext_vector_type(8))) short bf16x8;

constexpr int Bsz = 4096, Asz = 32, Isz = 256, Osz = 256;
constexpr int BM = 64, NKT = 8;
constexpr int NBLK = Asz * (Bsz / BM);   // 2048

// packed f32x2 -> bf16x2 (RNE); no builtin on gfx950
__device__ inline unsigned cvtpk(float lo, float hi) {
    unsigned r;
    asm("v_cvt_pk_bf16_f32 %0, %1, %2" : "=v"(r) : "v"(lo), "v"(hi));
    return r;
}

// async global->LDS DMA, 16B/lane; dest = wave-uniform base + lane*16 (linear)
__device__ inline void gl_lds16(const void* g, void* l) {
    __builtin_amdgcn_global_load_lds((const __attribute__((address_space(1))) void*)g,
                                     (__attribute__((address_space(3))) void*)l, 16, 0, 0);
}

// ---------------------------------------------------------------------------
// Pre-pack w [A,O,I] f32 -> bf16 fragment-linear: wf[((a*8+kt)*16+nf)*64+lane]
// = the 8 bf16 consumed by lane `lane` of B-fragment (a,kt,nf).
// o = nf*16 + (lane&15), i = kt*32 + (lane>>4)*8 .. +8
// ---------------------------------------------------------------------------
__global__ __launch_bounds__(256) void pack_w(const float* __restrict__ w,
                                              unsigned short* __restrict__ wf) {
    const int gid  = blockIdx.x * 256 + threadIdx.x;
    const int lane = gid & 63, nf = (gid >> 6) & 15, kt = (gid >> 10) & 7, a = gid >> 13;
    const int o  = nf * 16 + (lane & 15);
    const int i0 = kt * 32 + (lane >> 4) * 8;
    const float* s = w + (size_t)(a * Osz + o) * Isz + i0;
    f32x4 lo = *(const f32x4*)s, hi = *(const f32x4*)(s + 4);
    union { bf16x8 v; unsigned u[4]; } r;
    r.u[0] = cvtpk(lo[0], lo[1]); r.u[1] = cvtpk(lo[2], lo[3]);
    r.u[2] = cvtpk(hi[0], hi[1]); r.u[3] = cvtpk(hi[2], hi[3]);
    *(bf16x8*)(wf + (size_t)gid * 8) = r.v;
}

// ---------------------------------------------------------------------------
// Main GEMM: A staged f32 via global_load_lds (double-buffered, XOR-swizzled
// source, 16 KB LDS total); B read DIRECTLY global->VGPR from fragment-linear
// wf (L2-resident; the old LDS path was an identity per-lane round-trip).
// 4 blocks/CU (VGPR<=128) hide the per-kt barrier drain.
// ---------------------------------------------------------------------------
__global__ __launch_bounds__(256, 4) void al_gemm(const float* __restrict__ x,
                                                  const unsigned short* __restrict__ wf,
                                                  const float* __restrict__ bias,
                                                  float* __restrict__ out)
{
    __shared__ char sA[2][8192];    // 64 rows x 32 f32, chunk-swizzled

    // XCD-contiguous bijective swizzle (2048 % 8 == 0)
    const int p  = blockIdx.x;
    const int l  = (p & 7) * (NBLK / 8) + (p >> 3);
    const int a  = l >> 6;
    const int b0 = (l & 63) * BM;

    const int t    = threadIdx.x;
    const int wid  = t >> 6;
    const int lane = t & 63;
    const int llo  = lane & 15, lhi = lane >> 4;
    const int nb   = wid * 64;

    // A staging source (per-lane swizzled global addr; LDS dest linear).
    // phys chunk pc = wid*128 + j*64 + lane; row = pc>>3, q = (pc&7)^(row&7)
    const float* asrc[2];
#pragma unroll
    for (int j = 0; j < 2; ++j) {
        const int pc  = wid * 128 + j * 64 + lane;
        const int row = pc >> 3;
        const int q   = (pc & 7) ^ (row & 7);
        asrc[j] = x + ((size_t)(b0 + row) * Asz + a) * Isz + q * 4;
    }

    auto STAGE = [&](int buf, int kt) {
#pragma unroll
        for (int j = 0; j < 2; ++j)
            gl_lds16(asrc[j] + kt * 32, &sA[buf][wid * 2048 + j * 1024]);
    };

    // compute-side LDS addrs: logical chunk (row=llo, q=2*lhi) at
    // phys llo*128 + (q^(llo&7))*16
    const int q0     = (2 * lhi) ^ (llo & 7);
    const int abase0 = llo * 128 + q0 * 16;
    const int abase1 = llo * 128 + (q0 ^ 1) * 16;

    // B direct: wave's 4 frags are 4 contiguous 1KB lines per kt
    const unsigned short* bp = wf + (size_t)a * (Osz * Isz) + (wid * 4) * 512 + lane * 8;

    // bias folded into acc init (all 4 regs of a C-frag share col nb+n*16+llo)
    f32x4 acc[4][4];
#pragma unroll
    for (int n = 0; n < 4; ++n) {
        const float bv = bias[a * Osz + nb + n * 16 + llo];
#pragma unroll
        for (int m = 0; m < 4; ++m) acc[m][n] = (f32x4)(bv);
    }

    auto COMPUTE = [&](int buf, int kt) {
        bf16x8 bF[4];
#pragma unroll
        for (int n = 0; n < 4; ++n)                       // issue global loads first
            bF[n] = *(const bf16x8*)(bp + (size_t)kt * 8192 + n * 512);
        bf16x8 aF[4];
#pragma unroll
        for (int m = 0; m < 4; ++m) {                     // LDS reads overlap B latency
            f32x4 lo = *(const f32x4*)&sA[buf][abase0 + m * 2048];
            f32x4 hi = *(const f32x4*)&sA[buf][abase1 + m * 2048];
            union { bf16x8 v; unsigned u[4]; } r;
            r.u[0] = cvtpk(lo[0], lo[1]); r.u[1] = cvtpk(lo[2], lo[3]);
            r.u[2] = cvtpk(hi[0], hi[1]); r.u[3] = cvtpk(hi[2], hi[3]);
            aF[m] = r.v;
        }
#pragma unroll
        for (int m = 0; m < 4; ++m)
#pragma unroll
            for (int n = 0; n < 4; ++n)
                acc[m][n] = __builtin_amdgcn_mfma_f32_16x16x32_bf16(aF[m], bF[n], acc[m][n], 0, 0, 0);
    };

    STAGE(0, 0);
    __syncthreads();

    int cur = 0;
#pragma unroll
    for (int kt = 0; kt < NKT; ++kt) {
        if (kt < NKT - 1) STAGE(cur ^ 1, kt + 1);  // fire-and-forget DMA
        COMPUTE(cur, kt);
        __syncthreads();
        cur ^= 1;
    }

    // Epilogue: D[row = m*16 + lhi*4 + r][col = nb + n*16 + llo]
#pragma unroll
    for (int n = 0; n < 4; ++n) {
        const int col = nb + n * 16 + llo;
#pragma unroll
        for (int m = 0; m < 4; ++m) {
            const int row = b0 + m * 16 + lhi * 4;
            float* op = out + ((size_t)row * Asz + a) * Osz + col;
#pragma unroll
            for (int r = 0; r < 4; ++r)
                op[(size_t)r * Asz * Osz] = acc[m][n][r];
        }
    }
}

extern "C" void kernel_launch(void* const* d_in, const int* in_sizes, int n_in,
                              void* d_out, int out_size, void* d_ws, size_t ws_size,
                              hipStream_t stream) {
    const float* x    = (const float*)d_in[0];
    const float* w    = (const float*)d_in[1];
    const float* bias = (const float*)d_in[2];
    float* out        = (float*)d_out;
    unsigned short* wf = (unsigned short*)d_ws;   // 4 MB

    pack_w<<<dim3(Asz * NKT * 16 * 64 / 256), dim3(256), 0, stream>>>(w, wf);
    al_gemm<<<dim3(NBLK), dim3(256), 0, stream>>>(x, wf, bias, out);
}

// Round 6
// 79.298 us; speedup vs baseline: 1.0521x; 1.0521x over previous
//
#include <hip/hip_runtime.h>

typedef __attribute__((ext_vector_type(4))) float f32x4;
typedef __attribute__((ext_vector_type(8))) short bf16x8;

constexpr int Bsz = 4096, Asz = 32, Isz = 256, Osz = 256;
constexpr int BM = 32, NKT = 8;
constexpr int NBLK = Asz * (Bsz / BM);   // 4096

// packed f32x2 -> bf16x2 (RNE); no builtin on gfx950
__device__ inline unsigned cvtpk(float lo, float hi) {
    unsigned r;
    asm("v_cvt_pk_bf16_f32 %0, %1, %2" : "=v"(r) : "v"(lo), "v"(hi));
    return r;
}

// async global->LDS DMA, 16B/lane; dest = wave-uniform base + lane*16 (linear)
__device__ inline void gl_lds16(const void* g, void* l) {
    __builtin_amdgcn_global_load_lds((const __attribute__((address_space(1))) void*)g,
                                     (__attribute__((address_space(3))) void*)l, 16, 0, 0);
}

// ---------------------------------------------------------------------------
// Pre-pack w [A,O,I] f32 -> bf16 fragment-linear: wf[((a*8+kt)*16+nf)*64+lane]
// = the 8 bf16 consumed by lane `lane` of B-fragment (a,kt,nf).
// o = nf*16 + (lane&15), i = kt*32 + (lane>>4)*8 .. +8
// ---------------------------------------------------------------------------
__global__ __launch_bounds__(256) void pack_w(const float* __restrict__ w,
                                              unsigned short* __restrict__ wf) {
    const int gid  = blockIdx.x * 256 + threadIdx.x;
    const int lane = gid & 63, nf = (gid >> 6) & 15, kt = (gid >> 10) & 7, a = gid >> 13;
    const int o  = nf * 16 + (lane & 15);
    const int i0 = kt * 32 + (lane >> 4) * 8;
    const float* s = w + (size_t)(a * Osz + o) * Isz + i0;
    f32x4 lo = *(const f32x4*)s, hi = *(const f32x4*)(s + 4);
    union { bf16x8 v; unsigned u[4]; } r;
    r.u[0] = cvtpk(lo[0], lo[1]); r.u[1] = cvtpk(lo[2], lo[3]);
    r.u[2] = cvtpk(hi[0], hi[1]); r.u[3] = cvtpk(hi[2], hi[3]);
    *(bf16x8*)(wf + (size_t)gid * 8) = r.v;
}

// ---------------------------------------------------------------------------
// Main GEMM: BM=32 rows/block, FULL K staged up-front (32 KB LDS, 8 DMA/wave),
// ONE barrier total, then 8 barrier-free K-steps (B direct from L2-resident
// wf). 4 blocks/CU: DMA of fetching blocks overlaps compute of others.
// A source chunk-XOR-swizzled (linear LDS dest) -> 2-way ds_read_b128 (free).
// ---------------------------------------------------------------------------
__global__ __launch_bounds__(256, 4) void al_gemm(const float* __restrict__ x,
                                                  const unsigned short* __restrict__ wf,
                                                  const float* __restrict__ bias,
                                                  float* __restrict__ out)
{
    __shared__ char sA[32768];   // 32 rows x 64 chunks(16B), low-3 chunk-swizzled

    // XCD-contiguous bijective swizzle (4096 % 8 == 0): 512 ids/XCD = 4 a's.
    const int p  = blockIdx.x;
    const int l  = (p & 7) * (NBLK / 8) + (p >> 3);
    const int a  = l >> 7;
    const int b0 = (l & 127) * BM;

    const int t    = threadIdx.x;
    const int wid  = t >> 6;
    const int lane = t & 63;
    const int llo  = lane & 15, lhi = lane >> 4;
    const int nb   = wid * 64;

    // ---- stage whole 32x256 f32 tile: wave wid does rows wid*8..wid*8+7 ----
    // phys chunk-in-row = lane; global chunk cq = (lane&56) | ((lane&7)^j)
#pragma unroll
    for (int j = 0; j < 8; ++j) {
        const int row = wid * 8 + j;
        const int cq  = (lane & 56) | ((lane & 7) ^ j);
        const float* src = x + ((size_t)(b0 + row) * Asz + a) * Isz + cq * 4;
        gl_lds16(src, &sA[wid * 8192 + j * 1024]);
    }

    // B direct: wave's 4 frags per kt are 4 contiguous 1KB lines
    const unsigned short* bp = wf + (size_t)a * (Osz * Isz) + (wid * 4) * 512 + lane * 8;

    // bias folded into acc init (all 4 regs of a C-frag share col nb+n*16+llo)
    f32x4 acc[2][4];
#pragma unroll
    for (int n = 0; n < 4; ++n) {
        const float bv = bias[a * Osz + nb + n * 16 + llo];
#pragma unroll
        for (int m = 0; m < 2; ++m) acc[m][n] = (f32x4)(bv);
    }

    // compute-side LDS addr: row=m*16+llo, phys chunk = kt*8 + ((2*lhi)^(llo&7))
    const int abase = llo * 1024 + (((2 * lhi) ^ (llo & 7)) << 4);

    __syncthreads();   // the ONLY barrier: drains the 8 DMAs, joins waves

#pragma unroll
    for (int kt = 0; kt < NKT; ++kt) {
        bf16x8 bF[4];
#pragma unroll
        for (int n = 0; n < 4; ++n)
            bF[n] = *(const bf16x8*)(bp + (size_t)kt * 8192 + n * 512);
        bf16x8 aF[2];
#pragma unroll
        for (int m = 0; m < 2; ++m) {
            const int ad = m * 16384 + abase + kt * 128;
            f32x4 lo = *(const f32x4*)&sA[ad];
            f32x4 hi = *(const f32x4*)&sA[ad ^ 16];
            union { bf16x8 v; unsigned u[4]; } r;
            r.u[0] = cvtpk(lo[0], lo[1]); r.u[1] = cvtpk(lo[2], lo[3]);
            r.u[2] = cvtpk(hi[0], hi[1]); r.u[3] = cvtpk(hi[2], hi[3]);
            aF[m] = r.v;
        }
#pragma unroll
        for (int m = 0; m < 2; ++m)
#pragma unroll
            for (int n = 0; n < 4; ++n)
                acc[m][n] = __builtin_amdgcn_mfma_f32_16x16x32_bf16(aF[m], bF[n], acc[m][n], 0, 0, 0);
    }

    // Epilogue: D[row = m*16 + lhi*4 + r][col = nb + n*16 + llo]
#pragma unroll
    for (int n = 0; n < 4; ++n) {
        const int col = nb + n * 16 + llo;
#pragma unroll
        for (int m = 0; m < 2; ++m) {
            const int row = b0 + m * 16 + lhi * 4;
            float* op = out + ((size_t)row * Asz + a) * Osz + col;
#pragma unroll
            for (int r = 0; r < 4; ++r)
                op[(size_t)r * Asz * Osz] = acc[m][n][r];
        }
    }
}

extern "C" void kernel_launch(void* const* d_in, const int* in_sizes, int n_in,
                              void* d_out, int out_size, void* d_ws, size_t ws_size,
                              hipStream_t stream) {
    const float* x    = (const float*)d_in[0];
    const float* w    = (const float*)d_in[1];
    const float* bias = (const float*)d_in[2];
    float* out        = (float*)d_out;
    unsigned short* wf = (unsigned short*)d_ws;   // 4 MB

    pack_w<<<dim3(Asz * NKT * 16 * 64 / 256), dim3(256), 0, stream>>>(w, wf);
    al_gemm<<<dim3(NBLK), dim3(256), 0, stream>>>(x, wf, bias, out);
}